// Round 4
// baseline (293.567 us; speedup 1.0000x reference)
//
#include <hip/hip_runtime.h>

#define B_    2048
#define K_    32
#define D_    768
#define DICT_ 24576
#define C_    64

#define PAIR_CAP (1 << 18)      // 262144 entries, ~50x expected ~4800 pairs
#define CCHUNK   512            // dict columns per tile block (2^9)
#define DCHUNK   16             // d rows per tile block
#define NCC      (DICT_ / CCHUNK)   // 48
#define NDC      (D_ / DCHUNK)      // 48

// workspace layout (in floats):
//   [0, PAIR_CAP*4)        recArr: int4 {item, di, w_bits, 0}
//   [BDC_F, BDC_F+DICT_)   bdc
//   [CNT_F]                pairCount (int)
//   [T_F, T_F+PAIR_CAP)    tArr (int): tgt per pair (SoA so the filter reads 4B)
#define BDC_F (PAIR_CAP * 4)
#define CNT_F (BDC_F + DICT_)
#define T_F   (CNT_F + 1)
#define WS_FLOATS (T_F + PAIR_CAP)

// K1: bdc[r] = dot(up_encoder_w[r,:], b_dec). Streaming read @5.8 TB/s (measured).
// Block 0 also zero-inits the pair counter for the scan kernel (stream-ordered).
__global__ void bdc_kernel(const float* __restrict__ up_enc,
                           const float* __restrict__ b_dec,
                           float* __restrict__ bdc,
                           int* __restrict__ cnt) {
    if (blockIdx.x == 0 && threadIdx.x == 0) cnt[0] = 0;
    int wave = threadIdx.x >> 6;
    int lane = threadIdx.x & 63;
    int row  = blockIdx.x * 4 + wave;
    const float4* rp = (const float4*)(up_enc + (size_t)row * D_);
    const float4* bp = (const float4*)b_dec;
    float acc = 0.f;
    #pragma unroll
    for (int i = 0; i < 3; ++i) {
        float4 a = rp[lane + 64 * i];
        float4 b = bp[lane + 64 * i];
        acc += a.x * b.x + a.y * b.y + a.z * b.z + a.w * b.w;
    }
    #pragma unroll
    for (int off = 32; off; off >>= 1) acc += __shfl_xor(acc, off);
    if (lane == 0) bdc[row] = acc;
}

// K2: one wave per (b,i). Cheap unrolled readlane match-scan; emits compact
// pair list (item, di, tgt, w) and initializes out[item] with the bias.
__global__ void scan_kernel(const float* __restrict__ up_vals,
                            const float* __restrict__ bdc,
                            const int*   __restrict__ up_idx,
                            const int*   __restrict__ down_idx,
                            const int*   __restrict__ conn,
                            int*  __restrict__ cnt,
                            int*  __restrict__ tArr,
                            int4* __restrict__ recArr,
                            float* __restrict__ out) {
    int wave = threadIdx.x >> 6;
    int lane = threadIdx.x & 63;
    int item = blockIdx.x * 4 + wave;      // item = b*32 + i
    int b    = item >> 5;

    int di = down_idx[item];
    int allowed = conn[(size_t)di * C_ + lane];   // lane c holds slot c (C_==64)
    bool valid = allowed >= 0;
    int   myup  = up_idx[b * K_ + (lane & 31)];
    float myval = up_vals[b * K_ + (lane & 31)];

    if (lane == 0) out[item] = bdc[up_idx[item]];   // bias; pairs add on top

    unsigned jm = 0u;
    #pragma unroll
    for (int j = 0; j < K_; ++j) {
        int tgt = __builtin_amdgcn_readlane(myup, j);
        jm |= (valid && (allowed == tgt)) ? (1u << j) : 0u;
    }

    if (__ballot(jm != 0u)) {              // wave-uniform; ~7% of items
        #pragma unroll 1
        for (int j = 0; j < K_; ++j) {
            unsigned long long m = __ballot((jm >> j) & 1u);
            if (m != 0) {                  // wave-uniform
                int   t = __shfl(myup, j);           // computed by all lanes
                float w = (float)__popcll(m) * __shfl(myval, j);
                if (lane == 0) {
                    int pos = atomicAdd(cnt, 1);
                    if (pos < PAIR_CAP) {
                        tArr[pos]   = t;
                        recArr[pos] = make_int4(item, di, __float_as_int(w), 0);
                    }
                }
            }
        }
    }
}

// K3: grid (colchunk, dchunk). Block streams a [16 x 512] tile of up_dec into
// LDS (full-line coalesced -- the bdc pattern, 5.8 TB/s), filters the pair
// list for its column range (~100 pairs), then each pair does 16 MACs against
// the tile and atomicAdds into out. up_dec is read exactly once, streaming.
__global__ __launch_bounds__(256) void pair_dot_kernel(const float* __restrict__ A,
                                                       const float* __restrict__ down_enc,
                                                       const int*  __restrict__ cnt,
                                                       const int*  __restrict__ tArr,
                                                       const int4* __restrict__ recArr,
                                                       float* __restrict__ out) {
    __shared__ float tile[DCHUNK * CCHUNK];   // 32 KB
    __shared__ int   lidx[512];
    __shared__ int   lcnt;
    int tid = threadIdx.x;
    if (tid == 0) lcnt = 0;
    __syncthreads();

    int cc = blockIdx.x, dc = blockIdx.y;
    int c0 = cc * CCHUNK, d0 = dc * DCHUNK;

    int n = *cnt; if (n > PAIR_CAP) n = PAIR_CAP;
    for (int i = tid; i < n; i += 256) {
        if ((tArr[i] >> 9) == cc) {
            int s = atomicAdd(&lcnt, 1);
            if (s < 512) lidx[s] = i;
        }
    }
    __syncthreads();
    int ln = lcnt < 512 ? lcnt : 512;
    if (ln == 0) return;                      // ~skip tile load for empty chunks

    #pragma unroll
    for (int k = 0; k < 8; ++k) {             // 16 rows x 128 float4 = 2048 f4
        int l  = tid + 256 * k;
        int r  = l >> 7, fi = l & 127;
        ((float4*)tile)[l] = *(const float4*)(A + (size_t)(d0 + r) * DICT_ + c0 + 4 * fi);
    }
    __syncthreads();

    for (int i = tid; i < ln; i += 256) {
        int idx = lidx[i];
        int4 rec = recArr[idx];               // {item, di, w_bits, 0}
        int t = tArr[idx] - c0;
        const float4* dp = (const float4*)(down_enc + (size_t)rec.y * D_ + d0);
        float acc = 0.f;
        #pragma unroll
        for (int q = 0; q < 4; ++q) {         // 16 d's
            float4 dv = dp[q];
            acc += dv.x * tile[(4 * q + 0) * CCHUNK + t]
                 + dv.y * tile[(4 * q + 1) * CCHUNK + t]
                 + dv.z * tile[(4 * q + 2) * CCHUNK + t]
                 + dv.w * tile[(4 * q + 3) * CCHUNK + t];
        }
        atomicAdd(out + rec.x, __int_as_float(rec.z) * acc);
    }
}

// Fallback (no workspace): self-contained, column dots + inline bias.
__global__ void main_fallback(const float* __restrict__ up_vals,
                              const float* __restrict__ up_dec,
                              const float* __restrict__ down_enc,
                              const float* __restrict__ up_enc,
                              const float* __restrict__ b_dec,
                              const int*   __restrict__ up_idx,
                              const int*   __restrict__ down_idx,
                              const int*   __restrict__ conn,
                              float* __restrict__ out) {
    int wave = threadIdx.x >> 6;
    int lane = threadIdx.x & 63;
    int item = blockIdx.x * 4 + wave;
    int b    = item >> 5;

    int di = down_idx[item];
    int allowed = conn[(size_t)di * C_ + lane];
    bool valid = allowed >= 0;
    int   myup  = up_idx[b * K_ + (lane & 31)];
    float myval = up_vals[b * K_ + (lane & 31)];

    unsigned jm = 0u;
    #pragma unroll
    for (int j = 0; j < K_; ++j) {
        int tgt = __builtin_amdgcn_readlane(myup, j);
        jm |= (valid && (allowed == tgt)) ? (1u << j) : 0u;
    }

    float acc = 0.f;
    if (__ballot(jm != 0u)) {
        const float* drow = down_enc + (size_t)di * D_;
        #pragma unroll 1
        for (int j = 0; j < K_; ++j) {
            unsigned long long m = __ballot((jm >> j) & 1u);
            if (m != 0) {
                float w   = (float)__popcll(m) * __shfl(myval, j);
                int   tgt = __shfl(myup, j);
                const float* colp = up_dec + tgt;
                float partial = 0.f;
                #pragma unroll
                for (int ii = 0; ii < 12; ++ii) {
                    int d = lane + 64 * ii;
                    partial += drow[d] * colp[(size_t)d * DICT_];
                }
                acc += w * partial;
            }
        }
    }

    {   // inline bias
        int ui = up_idx[item];
        const float4* rp = (const float4*)(up_enc + (size_t)ui * D_);
        const float4* bp = (const float4*)b_dec;
        #pragma unroll
        for (int ii = 0; ii < 3; ++ii) {
            float4 a  = rp[lane + 64 * ii];
            float4 bb = bp[lane + 64 * ii];
            acc += a.x * bb.x + a.y * bb.y + a.z * bb.z + a.w * bb.w;
        }
    }

    #pragma unroll
    for (int off = 32; off; off >>= 1) acc += __shfl_xor(acc, off);
    if (lane == 0) out[item] = acc;
}

extern "C" void kernel_launch(void* const* d_in, const int* in_sizes, int n_in,
                              void* d_out, int out_size, void* d_ws, size_t ws_size,
                              hipStream_t stream) {
    (void)in_sizes; (void)n_in; (void)out_size;
    const float* up_vals  = (const float*)d_in[0];
    const float* up_dec   = (const float*)d_in[1];
    const float* down_enc = (const float*)d_in[2];
    const float* up_enc   = (const float*)d_in[3];
    const float* b_dec    = (const float*)d_in[4];
    const int*   up_idx   = (const int*)d_in[5];
    const int*   down_idx = (const int*)d_in[6];
    const int*   conn     = (const int*)d_in[7];
    float* out = (float*)d_out;

    if (ws_size < (size_t)WS_FLOATS * sizeof(float)) {
        main_fallback<<<(B_ * K_) / 4, 256, 0, stream>>>(up_vals, up_dec, down_enc,
                                                         up_enc, b_dec, up_idx,
                                                         down_idx, conn, out);
        return;
    }

    float* ws     = (float*)d_ws;
    int4*  recArr = (int4*)ws;
    float* bdc    = ws + BDC_F;
    int*   cnt    = (int*)(ws + CNT_F);
    int*   tArr   = (int*)(ws + T_F);

    bdc_kernel<<<DICT_ / 4, 256, 0, stream>>>(up_enc, b_dec, bdc, cnt);
    scan_kernel<<<(B_ * K_) / 4, 256, 0, stream>>>(up_vals, bdc, up_idx, down_idx,
                                                   conn, cnt, tArr, recArr, out);
    pair_dot_kernel<<<dim3(NCC, NDC), 256, 0, stream>>>(up_dec, down_enc, cnt,
                                                        tArr, recArr, out);
}

// Round 5
// 240.596 us; speedup vs baseline: 1.2202x; 1.2202x over previous
//
#include <hip/hip_runtime.h>

#define B_    2048
#define K_    32
#define D_    768
#define DICT_ 24576
#define C_    64

#define CCHUNK   512                 // dict columns per bucket / tile block
#define DCHUNK   16                  // d rows per tile block
#define NCC      (DICT_ / CCHUNK)    // 48 buckets / col-chunks
#define NDC      (D_ / DCHUNK)       // 48 d-chunks
#define BCAP     2048                // per-bucket capacity (~20x expected ~102)

// workspace layout (in floats/ints):
//   [0, NCC*BCAP*4)    recs: int4 {item, di, w_bits, tgt} per bucket (16B aligned)
//   [BDC_F, +DICT_)    bdc
//   [CNT_F, +NCC*16)   bucket counters, one per 64B line
#define REC_F 0
#define BDC_F (NCC * BCAP * 4)
#define CNT_F (BDC_F + DICT_)
#define WS_FLOATS (CNT_F + NCC * 16)

// K1: bdc[r] = dot(up_encoder_w[r,:], b_dec). Streaming read @5.8 TB/s (measured).
// Block 0 also zero-inits the 48 bucket counters (stream-ordered before scan).
__global__ void bdc_kernel(const float* __restrict__ up_enc,
                           const float* __restrict__ b_dec,
                           float* __restrict__ bdc,
                           int* __restrict__ cnt) {
    if (blockIdx.x == 0 && threadIdx.x < NCC) cnt[threadIdx.x * 16] = 0;
    int wave = threadIdx.x >> 6;
    int lane = threadIdx.x & 63;
    int row  = blockIdx.x * 4 + wave;
    const float4* rp = (const float4*)(up_enc + (size_t)row * D_);
    const float4* bp = (const float4*)b_dec;
    float acc = 0.f;
    #pragma unroll
    for (int i = 0; i < 3; ++i) {
        float4 a = rp[lane + 64 * i];
        float4 b = bp[lane + 64 * i];
        acc += a.x * b.x + a.y * b.y + a.z * b.z + a.w * b.w;
    }
    #pragma unroll
    for (int off = 32; off; off >>= 1) acc += __shfl_xor(acc, off);
    if (lane == 0) bdc[row] = acc;
}

// K2: one wave per (b,i). Cheap unrolled readlane match-scan; emits pairs into
// 48 column-chunk buckets (round-4 lesson: ONE global counter = ~4900 serialized
// same-line fetch-adds = 64 us; 48 spread counters run in parallel).
__global__ void scan_kernel(const float* __restrict__ up_vals,
                            const float* __restrict__ bdc,
                            const int*   __restrict__ up_idx,
                            const int*   __restrict__ down_idx,
                            const int*   __restrict__ conn,
                            int*  __restrict__ cnt,
                            int4* __restrict__ recs,
                            float* __restrict__ out) {
    int wave = threadIdx.x >> 6;
    int lane = threadIdx.x & 63;
    int item = blockIdx.x * 4 + wave;      // item = b*32 + i
    int b    = item >> 5;

    int di = down_idx[item];
    int allowed = conn[(size_t)di * C_ + lane];   // lane c holds slot c (C_==64)
    bool valid = allowed >= 0;
    int   myup  = up_idx[b * K_ + (lane & 31)];
    float myval = up_vals[b * K_ + (lane & 31)];

    if (lane == 0) out[item] = bdc[up_idx[item]];   // bias; pairs add on top

    unsigned jm = 0u;
    #pragma unroll
    for (int j = 0; j < K_; ++j) {
        int tgt = __builtin_amdgcn_readlane(myup, j);
        jm |= (valid && (allowed == tgt)) ? (1u << j) : 0u;
    }

    if (__ballot(jm != 0u)) {              // wave-uniform; ~7% of items
        #pragma unroll 1
        for (int j = 0; j < K_; ++j) {
            unsigned long long m = __ballot((jm >> j) & 1u);
            if (m != 0) {                  // wave-uniform
                int   t = __shfl(myup, j);
                float w = (float)__popcll(m) * __shfl(myval, j);
                if (lane == 0) {
                    int bi  = t >> 9;      // t / CCHUNK
                    int pos = atomicAdd(cnt + bi * 16, 1);
                    if (pos < BCAP)
                        recs[bi * BCAP + pos] = make_int4(item, di, __float_as_int(w), t);
                }
            }
        }
    }
}

// K3: grid (cc, dc). Block streams a [16 x 512] tile of up_dec into LDS
// (1-2KB bursts, one full pass over up_dec = 75.5 MB total), reads ONLY its
// own bucket (~102 records, coalesced), 16 MACs/pair vs LDS, atomicAdd to out.
__global__ __launch_bounds__(256) void pair_dot_kernel(const float* __restrict__ A,
                                                       const float* __restrict__ down_enc,
                                                       const int*  __restrict__ cnt,
                                                       const int4* __restrict__ recs,
                                                       float* __restrict__ out) {
    __shared__ float tile[DCHUNK * CCHUNK];   // 32 KB
    int tid = threadIdx.x;
    int cc = blockIdx.x, dc = blockIdx.y;
    int c0 = cc * CCHUNK, d0 = dc * DCHUNK;

    int n = cnt[cc * 16];
    if (n > BCAP) n = BCAP;
    if (n == 0) return;

    #pragma unroll
    for (int k = 0; k < 8; ++k) {             // 16 rows x 128 float4 = 2048 f4
        int l  = tid + 256 * k;
        int r  = l >> 7, fi = l & 127;
        ((float4*)tile)[l] = *(const float4*)(A + (size_t)(d0 + r) * DICT_ + c0 + 4 * fi);
    }
    __syncthreads();

    const int4* bucket = recs + (size_t)cc * BCAP;
    for (int i = tid; i < n; i += 256) {
        int4 rec = bucket[i];                 // {item, di, w_bits, tgt}
        int t = rec.w - c0;
        const float4* dp = (const float4*)(down_enc + (size_t)rec.y * D_ + d0);
        float acc = 0.f;
        #pragma unroll
        for (int q = 0; q < 4; ++q) {         // 16 d's
            float4 dv = dp[q];
            acc += dv.x * tile[(4 * q + 0) * CCHUNK + t]
                 + dv.y * tile[(4 * q + 1) * CCHUNK + t]
                 + dv.z * tile[(4 * q + 2) * CCHUNK + t]
                 + dv.w * tile[(4 * q + 3) * CCHUNK + t];
        }
        atomicAdd(out + rec.x, __int_as_float(rec.z) * acc);
    }
}

// Fallback (no workspace): self-contained, column dots + inline bias.
__global__ void main_fallback(const float* __restrict__ up_vals,
                              const float* __restrict__ up_dec,
                              const float* __restrict__ down_enc,
                              const float* __restrict__ up_enc,
                              const float* __restrict__ b_dec,
                              const int*   __restrict__ up_idx,
                              const int*   __restrict__ down_idx,
                              const int*   __restrict__ conn,
                              float* __restrict__ out) {
    int wave = threadIdx.x >> 6;
    int lane = threadIdx.x & 63;
    int item = blockIdx.x * 4 + wave;
    int b    = item >> 5;

    int di = down_idx[item];
    int allowed = conn[(size_t)di * C_ + lane];
    bool valid = allowed >= 0;
    int   myup  = up_idx[b * K_ + (lane & 31)];
    float myval = up_vals[b * K_ + (lane & 31)];

    unsigned jm = 0u;
    #pragma unroll
    for (int j = 0; j < K_; ++j) {
        int tgt = __builtin_amdgcn_readlane(myup, j);
        jm |= (valid && (allowed == tgt)) ? (1u << j) : 0u;
    }

    float acc = 0.f;
    if (__ballot(jm != 0u)) {
        const float* drow = down_enc + (size_t)di * D_;
        #pragma unroll 1
        for (int j = 0; j < K_; ++j) {
            unsigned long long m = __ballot((jm >> j) & 1u);
            if (m != 0) {
                float w   = (float)__popcll(m) * __shfl(myval, j);
                int   tgt = __shfl(myup, j);
                const float* colp = up_dec + tgt;
                float partial = 0.f;
                #pragma unroll
                for (int ii = 0; ii < 12; ++ii) {
                    int d = lane + 64 * ii;
                    partial += drow[d] * colp[(size_t)d * DICT_];
                }
                acc += w * partial;
            }
        }
    }

    {   // inline bias
        int ui = up_idx[item];
        const float4* rp = (const float4*)(up_enc + (size_t)ui * D_);
        const float4* bp = (const float4*)b_dec;
        #pragma unroll
        for (int ii = 0; ii < 3; ++ii) {
            float4 a  = rp[lane + 64 * ii];
            float4 bb = bp[lane + 64 * ii];
            acc += a.x * bb.x + a.y * bb.y + a.z * bb.z + a.w * bb.w;
        }
    }

    #pragma unroll
    for (int off = 32; off; off >>= 1) acc += __shfl_xor(acc, off);
    if (lane == 0) out[item] = acc;
}

extern "C" void kernel_launch(void* const* d_in, const int* in_sizes, int n_in,
                              void* d_out, int out_size, void* d_ws, size_t ws_size,
                              hipStream_t stream) {
    (void)in_sizes; (void)n_in; (void)out_size;
    const float* up_vals  = (const float*)d_in[0];
    const float* up_dec   = (const float*)d_in[1];
    const float* down_enc = (const float*)d_in[2];
    const float* up_enc   = (const float*)d_in[3];
    const float* b_dec    = (const float*)d_in[4];
    const int*   up_idx   = (const int*)d_in[5];
    const int*   down_idx = (const int*)d_in[6];
    const int*   conn     = (const int*)d_in[7];
    float* out = (float*)d_out;

    if (ws_size < (size_t)WS_FLOATS * sizeof(float)) {
        main_fallback<<<(B_ * K_) / 4, 256, 0, stream>>>(up_vals, up_dec, down_enc,
                                                         up_enc, b_dec, up_idx,
                                                         down_idx, conn, out);
        return;
    }

    float* ws   = (float*)d_ws;
    int4*  recs = (int4*)(ws + REC_F);
    float* bdc  = ws + BDC_F;
    int*   cnt  = (int*)(ws + CNT_F);

    bdc_kernel<<<DICT_ / 4, 256, 0, stream>>>(up_enc, b_dec, bdc, cnt);
    scan_kernel<<<(B_ * K_) / 4, 256, 0, stream>>>(up_vals, bdc, up_idx, down_idx,
                                                   conn, cnt, recs, out);
    pair_dot_kernel<<<dim3(NCC, NDC), 256, 0, stream>>>(up_dec, down_enc, cnt,
                                                        recs, out);
}